// Round 10
// baseline (154.825 us; speedup 1.0000x reference)
//
#include <hip/hip_runtime.h>

// Problem constants (from reference)
#define NNZ_TOT    2097152
#define N_CELLS    4096
#define N_GIN      20000     // input genes (len gene_idx, cols of x)
#define N_PRE      30000     // pretrained table rows
#define NUM_HID    128

// ---------------------------------------------------------------------------
// Workspace layout (256-B aligned):
//   ebf   : [N_GIN,128] bf16 compact table (~14.6k used rows = 3.7 MB < 4 MB
//           per-XCD L2 -> all gathers are ~200-cyc L2 hits)
//   mark  : [N_PRE]  -1 = unused, else compact id
//   mark2 : [N_GIN]  input gene j -> compact id
//   rp    : [N_CELLS+1] CSR row pointers
//   cnt   : [1] atomic id counter
//   ga    : [NNZ] per-nnz compact gene id (2-hop chains in the main kernel:
//           R9's xc->mark2->ebf 3-hop cost ~7 us vs R8's 2-hop)
// ---------------------------------------------------------------------------
#define EBF_OFF    0
#define EBF_BYTES  ((size_t)N_GIN * NUM_HID * 2)                     // 5.12 MB
#define MARK_OFF   (EBF_OFF + EBF_BYTES)
#define MARK_BYTES (((size_t)N_PRE * 4 + 255) & ~(size_t)255)
#define MARK2_OFF  (MARK_OFF + MARK_BYTES)
#define MARK2_PAD  (((size_t)N_GIN * 4 + 255) & ~(size_t)255)
#define RP_OFF     (MARK2_OFF + MARK2_PAD)
#define RP_BYTES   ((((size_t)(N_CELLS + 1) * 4) + 255) & ~(size_t)255)
#define CNT_OFF    (RP_OFF + RP_BYTES)
#define GA_OFF     (CNT_OFF + 256)
#define GA_BYTES   ((size_t)NNZ_TOT * 4)                             // 8 MB
#define WS_NEED    (GA_OFF + GA_BYTES)

__device__ __forceinline__ unsigned short f2bf(float f) {
    union { float f; unsigned u; } c; c.f = f;
    unsigned u = c.u;
    u += 0x7fffu + ((u >> 16) & 1u);    // round-to-nearest-even
    return (unsigned short)(u >> 16);
}

// ---------------------------------------------------------------------------
// K1: first-touch compact-id assignment (CAS winner assigns dense id).
// ---------------------------------------------------------------------------
__global__ __launch_bounds__(256) void assign_ids_kernel(
    const int* __restrict__ gidx, int* __restrict__ mark, int* __restrict__ cnt)
{
    const int j = blockIdx.x * blockDim.x + threadIdx.x;
    if (j < N_GIN) {
        const int g = gidx[j];
        if (atomicCAS(&mark[g], -1, -2) == -1) {
            const int id = atomicAdd(cnt, 1);
            mark[g] = id;
        }
    }
}

// ---------------------------------------------------------------------------
// K2: build compact bf16 table + mark2. 32 threads per input gene j.
// ---------------------------------------------------------------------------
__global__ __launch_bounds__(256) void build_table_kernel(
    const int* __restrict__ gidx, const int* __restrict__ mark,
    const float* __restrict__ embs, unsigned short* __restrict__ ebf,
    int* __restrict__ mark2)
{
    const int tid = blockIdx.x * blockDim.x + threadIdx.x;
    const int j = tid >> 5;
    const int k = tid & 31;
    if (j >= N_GIN) return;
    const int g  = gidx[j];
    const int id = mark[g];
    if (k == 0) mark2[j] = id;
    const float4 f = *reinterpret_cast<const float4*>(
        &embs[(long)g * NUM_HID + k * 4]);
    ushort4 o;
    o.x = f2bf(f.x); o.y = f2bf(f.y); o.z = f2bf(f.z); o.w = f2bf(f.w);
    *reinterpret_cast<ushort4*>(&ebf[(long)id * NUM_HID + k * 4]) = o;
}

// ---------------------------------------------------------------------------
// K3: fuse per-nnz gene id: ga[i] = mark2[xc[i]]  (2-hop main chains).
// ---------------------------------------------------------------------------
__global__ __launch_bounds__(256) void fuse_ga_kernel(
    const int* __restrict__ xc, const int* __restrict__ mark2,
    int* __restrict__ ga)
{
    const int i = blockIdx.x * blockDim.x + threadIdx.x;
    if (i < NNZ_TOT) ga[i] = mark2[xc[i]];
}

// ---------------------------------------------------------------------------
// K4: CSR row pointers.
// ---------------------------------------------------------------------------
__global__ __launch_bounds__(256) void row_ptr_kernel(
    const int* __restrict__ xr, int* __restrict__ rp)
{
    const int r = blockIdx.x * blockDim.x + threadIdx.x;
    if (r <= N_CELLS) {
        int lo = 0, hi = NNZ_TOT;
        while (lo < hi) {
            const int mid = (lo + hi) >> 1;
            if (xr[mid] < r) lo = mid + 1; else hi = mid;
        }
        rp[r] = lo;
    }
}

// ---------------------------------------------------------------------------
// Main: one wave per output row; zero atomics; 2-hop chains (ga -> ebf);
// compact L2-resident table; non-temporal COO stream reads (don't evict
// the table from L2). Lane = (quad = lane>>4, sub = lane&15); sub owns
// dims [sub*8, sub*8+8), quad picks 1 of 4 consecutive nnz -> one
// global_load_dwordx4 = 4 complete 256-B rows. 32 nnz/iter = 8 chains.
// ---------------------------------------------------------------------------
__device__ __forceinline__ void fma8(uint4 f, float vv, float4& a0, float4& a1) {
    a0.x = fmaf(vv, __uint_as_float(f.x << 16),         a0.x);
    a0.y = fmaf(vv, __uint_as_float(f.x & 0xffff0000u), a0.y);
    a0.z = fmaf(vv, __uint_as_float(f.y << 16),         a0.z);
    a0.w = fmaf(vv, __uint_as_float(f.y & 0xffff0000u), a0.w);
    a1.x = fmaf(vv, __uint_as_float(f.z << 16),         a1.x);
    a1.y = fmaf(vv, __uint_as_float(f.z & 0xffff0000u), a1.y);
    a1.z = fmaf(vv, __uint_as_float(f.w << 16),         a1.z);
    a1.w = fmaf(vv, __uint_as_float(f.w & 0xffff0000u), a1.w);
}

__global__ __launch_bounds__(256) void omics_row_kernel(
    const float*          __restrict__ xv,   // [NNZ] values
    const int*            __restrict__ ga,   // [NNZ] compact gene ids
    const int*            __restrict__ rp,   // [N_CELLS+1]
    const unsigned short* __restrict__ ebf,  // compact bf16 table
    float*                __restrict__ out)  // [N_CELLS,128]
{
    const int wave = (blockIdx.x * blockDim.x + threadIdx.x) >> 6;
    const int lane = threadIdx.x & 63;
    const int sub  = lane & 15;
    const int quad = lane >> 4;
    const int r    = __builtin_amdgcn_readfirstlane(wave);
    if (r >= N_CELLS) return;

    const int lo = rp[r];
    const int hi = rp[r + 1];
    const int h8 = sub * 8;

    float4 a0 = make_float4(0.f, 0.f, 0.f, 0.f);
    float4 a1 = make_float4(0.f, 0.f, 0.f, 0.f);
    float4 b0 = make_float4(0.f, 0.f, 0.f, 0.f);
    float4 b1 = make_float4(0.f, 0.f, 0.f, 0.f);

    int i = lo;
    for (; i + 32 <= hi; i += 32) {
        const int i0 = i + quad;
        const int g0 = __builtin_nontemporal_load(&ga[i0]);
        const int g1 = __builtin_nontemporal_load(&ga[i0 + 4]);
        const int g2 = __builtin_nontemporal_load(&ga[i0 + 8]);
        const int g3 = __builtin_nontemporal_load(&ga[i0 + 12]);
        const int g4 = __builtin_nontemporal_load(&ga[i0 + 16]);
        const int g5 = __builtin_nontemporal_load(&ga[i0 + 20]);
        const int g6 = __builtin_nontemporal_load(&ga[i0 + 24]);
        const int g7 = __builtin_nontemporal_load(&ga[i0 + 28]);
        const float v0 = __builtin_nontemporal_load(&xv[i0]);
        const float v1 = __builtin_nontemporal_load(&xv[i0 + 4]);
        const float v2 = __builtin_nontemporal_load(&xv[i0 + 8]);
        const float v3 = __builtin_nontemporal_load(&xv[i0 + 12]);
        const float v4 = __builtin_nontemporal_load(&xv[i0 + 16]);
        const float v5 = __builtin_nontemporal_load(&xv[i0 + 20]);
        const float v6 = __builtin_nontemporal_load(&xv[i0 + 24]);
        const float v7 = __builtin_nontemporal_load(&xv[i0 + 28]);

        const uint4 f0 = *reinterpret_cast<const uint4*>(&ebf[(long)g0 * NUM_HID + h8]);
        const uint4 f1 = *reinterpret_cast<const uint4*>(&ebf[(long)g1 * NUM_HID + h8]);
        const uint4 f2 = *reinterpret_cast<const uint4*>(&ebf[(long)g2 * NUM_HID + h8]);
        const uint4 f3 = *reinterpret_cast<const uint4*>(&ebf[(long)g3 * NUM_HID + h8]);
        const uint4 f4 = *reinterpret_cast<const uint4*>(&ebf[(long)g4 * NUM_HID + h8]);
        const uint4 f5 = *reinterpret_cast<const uint4*>(&ebf[(long)g5 * NUM_HID + h8]);
        const uint4 f6 = *reinterpret_cast<const uint4*>(&ebf[(long)g6 * NUM_HID + h8]);
        const uint4 f7 = *reinterpret_cast<const uint4*>(&ebf[(long)g7 * NUM_HID + h8]);

        fma8(f0, v0, a0, a1);
        fma8(f1, v1, b0, b1);
        fma8(f2, v2, a0, a1);
        fma8(f3, v3, b0, b1);
        fma8(f4, v4, a0, a1);
        fma8(f5, v5, b0, b1);
        fma8(f6, v6, a0, a1);
        fma8(f7, v7, b0, b1);
    }
    // tail: 4 nnz at a time, predicated by clamped index + zeroed value
    for (; i < hi; i += 4) {
        const int  idx = i + quad;
        const bool ok  = idx < hi;
        const int   gg = ga[ok ? idx : (hi - 1)];
        const float vv = ok ? xv[idx] : 0.f;
        const uint4 f  = *reinterpret_cast<const uint4*>(&ebf[(long)gg * NUM_HID + h8]);
        fma8(f, vv, a0, a1);
    }

    a0.x += b0.x; a0.y += b0.y; a0.z += b0.z; a0.w += b0.w;
    a1.x += b1.x; a1.y += b1.y; a1.z += b1.z; a1.w += b1.w;

    // cross-quad reduction (quads hold disjoint nnz subsets of the row)
    a0.x += __shfl_xor(a0.x, 16); a0.x += __shfl_xor(a0.x, 32);
    a0.y += __shfl_xor(a0.y, 16); a0.y += __shfl_xor(a0.y, 32);
    a0.z += __shfl_xor(a0.z, 16); a0.z += __shfl_xor(a0.z, 32);
    a0.w += __shfl_xor(a0.w, 16); a0.w += __shfl_xor(a0.w, 32);
    a1.x += __shfl_xor(a1.x, 16); a1.x += __shfl_xor(a1.x, 32);
    a1.y += __shfl_xor(a1.y, 16); a1.y += __shfl_xor(a1.y, 32);
    a1.z += __shfl_xor(a1.z, 16); a1.z += __shfl_xor(a1.z, 32);
    a1.w += __shfl_xor(a1.w, 16); a1.w += __shfl_xor(a1.w, 32);

    if (quad == 0) {
        float* o = &out[(long)r * NUM_HID + h8];
        *reinterpret_cast<float4*>(o)     = a0;
        *reinterpret_cast<float4*>(o + 4) = a1;
    }
}

// ---------------------------------------------------------------------------
// Fallback (ws too small): fp32, one wave per row, inline binary search.
// ---------------------------------------------------------------------------
__global__ __launch_bounds__(256) void omics_fp32_row_kernel(
    const float* __restrict__ xv, const int* __restrict__ xr,
    const int* __restrict__ xc, const int* __restrict__ gidx,
    const float* __restrict__ embs, float* __restrict__ out)
{
    const int wave = (blockIdx.x * blockDim.x + threadIdx.x) >> 6;
    const int lane = threadIdx.x & 63;
    if (wave >= N_CELLS) return;
    int lo = 0, hi = NNZ_TOT;
    while (lo < hi) { int m = (lo + hi) >> 1; if (xr[m] < wave) lo = m + 1; else hi = m; }
    int lo2 = lo, hi2 = NNZ_TOT;
    while (lo2 < hi2) { int m = (lo2 + hi2) >> 1; if (xr[m] < wave + 1) lo2 = m + 1; else hi2 = m; }
    const int h = lane * 2;
    float2 acc = make_float2(0.f, 0.f);
    for (int i = lo; i < lo2; ++i) {
        const float v = xv[i];
        const int   g = gidx[xc[i]];
        const float2 f = *reinterpret_cast<const float2*>(&embs[(long)g * NUM_HID + h]);
        acc.x = fmaf(v, f.x, acc.x);
        acc.y = fmaf(v, f.y, acc.y);
    }
    *reinterpret_cast<float2*>(&out[(long)wave * NUM_HID + h]) = acc;
}

extern "C" void kernel_launch(void* const* d_in, const int* in_sizes, int n_in,
                              void* d_out, int out_size, void* d_ws, size_t ws_size,
                              hipStream_t stream) {
    const float* xv   = (const float*)d_in[0];
    const int*   xr   = (const int*)  d_in[1];
    const int*   xc   = (const int*)  d_in[2];
    const int*   gidx = (const int*)  d_in[3];
    const float* embs = (const float*)d_in[4];
    float*       out  = (float*)d_out;

    if (ws_size >= WS_NEED) {
        unsigned short* ebf   = (unsigned short*)((char*)d_ws + EBF_OFF);
        int*            mark  = (int*)((char*)d_ws + MARK_OFF);
        int*            mark2 = (int*)((char*)d_ws + MARK2_OFF);
        int*            rp    = (int*)((char*)d_ws + RP_OFF);
        int*            cnt   = (int*)((char*)d_ws + CNT_OFF);
        int*            ga    = (int*)((char*)d_ws + GA_OFF);

        hipMemsetAsync(mark, 0xFF, (size_t)N_PRE * 4, stream);   // mark = -1
        hipMemsetAsync(cnt, 0, 4, stream);

        assign_ids_kernel<<<(N_GIN + 255) / 256, 256, 0, stream>>>(gidx, mark, cnt);
        build_table_kernel<<<(N_GIN * 32 + 255) / 256, 256, 0, stream>>>(
            gidx, mark, embs, ebf, mark2);
        fuse_ga_kernel<<<(NNZ_TOT + 255) / 256, 256, 0, stream>>>(xc, mark2, ga);
        row_ptr_kernel<<<(N_CELLS + 256) / 256, 256, 0, stream>>>(xr, rp);

        omics_row_kernel<<<(N_CELLS * 64) / 256, 256, 0, stream>>>(
            xv, ga, rp, ebf, out);
    } else {
        omics_fp32_row_kernel<<<(N_CELLS * 64) / 256, 256, 0, stream>>>(
            xv, xr, xc, gidx, embs, out);
    }
}

// Round 11
// 129.150 us; speedup vs baseline: 1.1988x; 1.1988x over previous
//
#include <hip/hip_runtime.h>

// Problem constants (from reference)
#define NNZ_TOT    2097152
#define N_CELLS    4096
#define N_GIN      20000     // input genes
#define N_PRE      30000     // pretrained table rows
#define NUM_HID    128

// Workspace: g_arr [NNZ] int, ebf [N_PRE,128] bf16, rp [N_CELLS+1] int
#define GA_OFF    0
#define GA_BYTES  ((size_t)NNZ_TOT * 4)                       // 8 MB
#define EBF_OFF   (GA_OFF + GA_BYTES)
#define EBF_BYTES ((size_t)N_PRE * NUM_HID * 2)               // 7.68 MB
#define RP_OFF    (EBF_OFF + EBF_BYTES)
#define RP_BYTES  ((((size_t)(N_CELLS + 1) * 4) + 255) & ~(size_t)255)
#define WS_NEED   (RP_OFF + RP_BYTES)

__device__ __forceinline__ unsigned short f2bf(float f) {
    union { float f; unsigned u; } c; c.f = f;
    unsigned u = c.u;
    u += 0x7fffu + ((u >> 16) & 1u);    // round-to-nearest-even
    return (unsigned short)(u >> 16);
}

// ---------------------------------------------------------------------------
// P1: fused precompute — blocks [0, NB_GA) do g_arr[i] = gidx[xc[i]];
// blocks [NB_GA, NB_GA+NB_RP) do CSR row pointers (binary search).
// ---------------------------------------------------------------------------
#define NB_GA ((NNZ_TOT + 255) / 256)         // 8192 blocks
#define NB_RP ((N_CELLS + 256) / 256)         // 17 blocks

__global__ __launch_bounds__(256) void precompute_kernel(
    const int* __restrict__ xc, const int* __restrict__ gidx,
    const int* __restrict__ xr, int* __restrict__ g_arr,
    int* __restrict__ rp)
{
    const int b = blockIdx.x;
    if (b < NB_GA) {
        const int i = b * 256 + threadIdx.x;
        if (i < NNZ_TOT) g_arr[i] = gidx[xc[i]];
    } else {
        const int r = (b - NB_GA) * 256 + threadIdx.x;
        if (r <= N_CELLS) {
            int lo = 0, hi = NNZ_TOT;
            while (lo < hi) {
                const int mid = (lo + hi) >> 1;
                if (xr[mid] < r) lo = mid + 1; else hi = mid;
            }
            rp[r] = lo;
        }
    }
}

// ---------------------------------------------------------------------------
// P2: bf16 copy of the embedding table (rows 512 B -> 256 B). Halves the
// irreducible gather volume: 2M nnz x 256 B = 512 MB of L2->L1 traffic.
// ---------------------------------------------------------------------------
__global__ __launch_bounds__(256) void convert_embs_kernel(
    const float* __restrict__ embs, unsigned short* __restrict__ ebf)
{
    const int i = blockIdx.x * blockDim.x + threadIdx.x;   // per 4 floats
    if (i * 4 < N_PRE * NUM_HID) {
        const float4 f = *reinterpret_cast<const float4*>(&embs[i * 4]);
        ushort4 o;
        o.x = f2bf(f.x); o.y = f2bf(f.y); o.z = f2bf(f.z); o.w = f2bf(f.w);
        *reinterpret_cast<ushort4*>(&ebf[i * 4]) = o;
    }
}

// ---------------------------------------------------------------------------
// Main: one wave per output row; zero atomics; 2-hop chains (g_arr -> ebf).
// Lane = (quad = lane>>4, sub = lane&15); sub owns dims [sub*8, sub*8+8)
// (16 B bf16), quad picks 1 of 4 consecutive nnz -> one global_load_dwordx4
// fetches 4 complete 256-B rows, every fetched byte consumed.
// 32 nnz/iter = 8 independent gather chains. Plain loads (R10's nontemporal
// hints were neutral-to-harmful). No private arrays (R5/R6: promote-alloca
// moved them to LDS+scratch); no min-wave caps (R5: VGPR spill); no atomics
// (R7: 325 MB coherent-point writes).
// Measured invariant across R4/R8/R9/R10: gather service ~19 B/cyc/CU ->
// per-CU miss-tracking (MSHR x L2-latency) limit; structure-insensitive.
// ---------------------------------------------------------------------------
__device__ __forceinline__ void fma8(uint4 f, float vv, float4& a0, float4& a1) {
    a0.x = fmaf(vv, __uint_as_float(f.x << 16),         a0.x);
    a0.y = fmaf(vv, __uint_as_float(f.x & 0xffff0000u), a0.y);
    a0.z = fmaf(vv, __uint_as_float(f.y << 16),         a0.z);
    a0.w = fmaf(vv, __uint_as_float(f.y & 0xffff0000u), a0.w);
    a1.x = fmaf(vv, __uint_as_float(f.z << 16),         a1.x);
    a1.y = fmaf(vv, __uint_as_float(f.z & 0xffff0000u), a1.y);
    a1.z = fmaf(vv, __uint_as_float(f.w << 16),         a1.z);
    a1.w = fmaf(vv, __uint_as_float(f.w & 0xffff0000u), a1.w);
}

__global__ __launch_bounds__(256) void omics_row_kernel(
    const float*          __restrict__ xv,    // [NNZ] values
    const int*            __restrict__ ga,    // [NNZ] gene ids (fused)
    const int*            __restrict__ rp,    // [N_CELLS+1]
    const unsigned short* __restrict__ ebf,   // [N_PRE,128] bf16
    float*                __restrict__ out)   // [N_CELLS,128]
{
    const int wave = (blockIdx.x * blockDim.x + threadIdx.x) >> 6;
    const int lane = threadIdx.x & 63;
    const int sub  = lane & 15;
    const int quad = lane >> 4;
    const int r    = __builtin_amdgcn_readfirstlane(wave);
    if (r >= N_CELLS) return;

    const int lo = rp[r];
    const int hi = rp[r + 1];
    const int h8 = sub * 8;

    float4 a0 = make_float4(0.f, 0.f, 0.f, 0.f);
    float4 a1 = make_float4(0.f, 0.f, 0.f, 0.f);
    float4 b0 = make_float4(0.f, 0.f, 0.f, 0.f);
    float4 b1 = make_float4(0.f, 0.f, 0.f, 0.f);

    int i = lo;
    for (; i + 32 <= hi; i += 32) {
        const int i0 = i + quad;
        const int g0 = ga[i0];      const float v0 = xv[i0];
        const int g1 = ga[i0 + 4];  const float v1 = xv[i0 + 4];
        const int g2 = ga[i0 + 8];  const float v2 = xv[i0 + 8];
        const int g3 = ga[i0 + 12]; const float v3 = xv[i0 + 12];
        const int g4 = ga[i0 + 16]; const float v4 = xv[i0 + 16];
        const int g5 = ga[i0 + 20]; const float v5 = xv[i0 + 20];
        const int g6 = ga[i0 + 24]; const float v6 = xv[i0 + 24];
        const int g7 = ga[i0 + 28]; const float v7 = xv[i0 + 28];

        const uint4 f0 = *reinterpret_cast<const uint4*>(&ebf[(long)g0 * NUM_HID + h8]);
        const uint4 f1 = *reinterpret_cast<const uint4*>(&ebf[(long)g1 * NUM_HID + h8]);
        const uint4 f2 = *reinterpret_cast<const uint4*>(&ebf[(long)g2 * NUM_HID + h8]);
        const uint4 f3 = *reinterpret_cast<const uint4*>(&ebf[(long)g3 * NUM_HID + h8]);
        const uint4 f4 = *reinterpret_cast<const uint4*>(&ebf[(long)g4 * NUM_HID + h8]);
        const uint4 f5 = *reinterpret_cast<const uint4*>(&ebf[(long)g5 * NUM_HID + h8]);
        const uint4 f6 = *reinterpret_cast<const uint4*>(&ebf[(long)g6 * NUM_HID + h8]);
        const uint4 f7 = *reinterpret_cast<const uint4*>(&ebf[(long)g7 * NUM_HID + h8]);

        fma8(f0, v0, a0, a1);
        fma8(f1, v1, b0, b1);
        fma8(f2, v2, a0, a1);
        fma8(f3, v3, b0, b1);
        fma8(f4, v4, a0, a1);
        fma8(f5, v5, b0, b1);
        fma8(f6, v6, a0, a1);
        fma8(f7, v7, b0, b1);
    }
    // tail: 4 nnz at a time, predicated by clamped index + zeroed value
    for (; i < hi; i += 4) {
        const int  idx = i + quad;
        const bool ok  = idx < hi;
        const int   gg = ga[ok ? idx : (hi - 1)];
        const float vv = ok ? xv[idx] : 0.f;
        const uint4 f  = *reinterpret_cast<const uint4*>(&ebf[(long)gg * NUM_HID + h8]);
        fma8(f, vv, a0, a1);
    }

    a0.x += b0.x; a0.y += b0.y; a0.z += b0.z; a0.w += b0.w;
    a1.x += b1.x; a1.y += b1.y; a1.z += b1.z; a1.w += b1.w;

    // cross-quad reduction (quads hold disjoint nnz subsets of the row)
    a0.x += __shfl_xor(a0.x, 16); a0.x += __shfl_xor(a0.x, 32);
    a0.y += __shfl_xor(a0.y, 16); a0.y += __shfl_xor(a0.y, 32);
    a0.z += __shfl_xor(a0.z, 16); a0.z += __shfl_xor(a0.z, 32);
    a0.w += __shfl_xor(a0.w, 16); a0.w += __shfl_xor(a0.w, 32);
    a1.x += __shfl_xor(a1.x, 16); a1.x += __shfl_xor(a1.x, 32);
    a1.y += __shfl_xor(a1.y, 16); a1.y += __shfl_xor(a1.y, 32);
    a1.z += __shfl_xor(a1.z, 16); a1.z += __shfl_xor(a1.z, 32);
    a1.w += __shfl_xor(a1.w, 16); a1.w += __shfl_xor(a1.w, 32);

    if (quad == 0) {
        float* o = &out[(long)r * NUM_HID + h8];
        *reinterpret_cast<float4*>(o)     = a0;
        *reinterpret_cast<float4*>(o + 4) = a1;
    }
}

// ---------------------------------------------------------------------------
// Fallback (ws too small): fp32, one wave per row, inline binary search.
// ---------------------------------------------------------------------------
__global__ __launch_bounds__(256) void omics_fp32_row_kernel(
    const float* __restrict__ xv, const int* __restrict__ xr,
    const int* __restrict__ xc, const int* __restrict__ gidx,
    const float* __restrict__ embs, float* __restrict__ out)
{
    const int wave = (blockIdx.x * blockDim.x + threadIdx.x) >> 6;
    const int lane = threadIdx.x & 63;
    if (wave >= N_CELLS) return;
    int lo = 0, hi = NNZ_TOT;
    while (lo < hi) { int m = (lo + hi) >> 1; if (xr[m] < wave) lo = m + 1; else hi = m; }
    int lo2 = lo, hi2 = NNZ_TOT;
    while (lo2 < hi2) { int m = (lo2 + hi2) >> 1; if (xr[m] < wave + 1) lo2 = m + 1; else hi2 = m; }
    const int h = lane * 2;
    float2 acc = make_float2(0.f, 0.f);
    for (int i = lo; i < lo2; ++i) {
        const float v = xv[i];
        const int   g = gidx[xc[i]];
        const float2 f = *reinterpret_cast<const float2*>(&embs[(long)g * NUM_HID + h]);
        acc.x = fmaf(v, f.x, acc.x);
        acc.y = fmaf(v, f.y, acc.y);
    }
    *reinterpret_cast<float2*>(&out[(long)wave * NUM_HID + h]) = acc;
}

extern "C" void kernel_launch(void* const* d_in, const int* in_sizes, int n_in,
                              void* d_out, int out_size, void* d_ws, size_t ws_size,
                              hipStream_t stream) {
    const float* xv   = (const float*)d_in[0];
    const int*   xr   = (const int*)  d_in[1];
    const int*   xc   = (const int*)  d_in[2];
    const int*   gidx = (const int*)  d_in[3];
    const float* embs = (const float*)d_in[4];
    float*       out  = (float*)d_out;

    if (ws_size >= WS_NEED) {
        int*            ga  = (int*)((char*)d_ws + GA_OFF);
        unsigned short* ebf = (unsigned short*)((char*)d_ws + EBF_OFF);
        int*            rp  = (int*)((char*)d_ws + RP_OFF);

        precompute_kernel<<<NB_GA + NB_RP, 256, 0, stream>>>(xc, gidx, xr, ga, rp);
        convert_embs_kernel<<<(N_PRE * NUM_HID / 4 + 255) / 256, 256, 0, stream>>>(embs, ebf);

        omics_row_kernel<<<(N_CELLS * 64) / 256, 256, 0, stream>>>(
            xv, ga, rp, ebf, out);
    } else {
        omics_fp32_row_kernel<<<(N_CELLS * 64) / 256, 256, 0, stream>>>(
            xv, xr, xc, gidx, embs, out);
    }
}